// Round 14
// baseline (82.972 us; speedup 1.0000x reference)
//
#include <hip/hip_runtime.h>

#define NBINS  128               // uniform bins in x-space over [-6, 6]
#define NCLS   20
#define CDIM   21
#define HW     (512 * 512)
#define NPIX   (8 * HW)
#define NCHUNK 1024
#define CHUNK  (NPIX / NCHUNK)   // 2048 pixels/block; divides HW
#define HSZ    (NCLS * NBINS)    // 2560 packed u32 per block
#define NRED   320               // reduce blocks (8 bins each)
#define XSCALE 10.6666667f       // 128/12
#define XBIAS  64.0f             // 6 * XSCALE

__device__ __forceinline__ float4 gld_f4(const float* p) {
    float4 r;
    asm volatile("global_load_dwordx4 %0, %1, off" : "=v"(r) : "v"(p));
    return r;
}
__device__ __forceinline__ int4 gld_i4(const int* p) {
    int4 r;
    asm volatile("global_load_dwordx4 %0, %1, off" : "=v"(r) : "v"(p));
    return r;
}

// One block = 2048 pixels via 512 threads (4 px/thread, single tile), all 20
// classes, binned in x-space (monotone in sigmoid; positives at -x on the
// symmetric grid). 4 phases of 5 channels, 1-ahead counted-vmcnt pipeline
// (uniform vmcnt(5); drain only at the last phase). 24 waves/CU.
// Output: per-block packed u32 histogram (cnt lo16 | pos hi16), plain stores.
__global__ __launch_bounds__(512, 6) void lovasz_hist(const float* __restrict__ pred,
                                                      const int* __restrict__ label,
                                                      unsigned* __restrict__ g_part,
                                                      unsigned* __restrict__ ctr) {
    __shared__ unsigned s_hist[HSZ];   // 10 KB
    const int tid = threadIdx.x;
    if (blockIdx.x == 0 && tid == 0) ctr[0] = 0u;   // reset ticket for reduce

    const long base = (long)blockIdx.x * CHUNK;
    const int  b    = (int)(base / HW);
    const long hw0  = base - (long)b * HW;
    const float* pbase = pred + ((long)b * CDIM + 1) * HW + hw0 + tid * 4;

    // Prologue: label + G0 + G1 issued (11 outstanding).
    const int4 l = gld_i4(label + base + tid * 4);
    float4 buf[2][5];
#pragma unroll
    for (int gg = 0; gg < 2; ++gg)
#pragma unroll
        for (int k = 0; k < 5; ++k)
            buf[gg][k] = gld_f4(pbase + (long)(gg * 5 + k) * HW);

    // zero LDS + barrier under the load latency
    for (int i = tid; i < HSZ; i += 512) s_hist[i] = 0u;
    __syncthreads();

    auto compute5 = [&](const float4* x, int cbase) {
#pragma unroll
        for (int j = 0; j < 4; ++j) {
            const int lv = (j == 0) ? l.x : (j == 1) ? l.y : (j == 2) ? l.z : l.w;
#pragma unroll
            for (int k = 0; k < 5; ++k) {
                const float xv = (j == 0) ? x[k].x : (j == 1) ? x[k].y
                               : (j == 2) ? x[k].z : x[k].w;
                const bool  pos = (lv == cbase + k + 1);
                const float t   = pos ? -xv : xv;     // error = sigmoid(t)
                const float bf  = fminf(fmaxf(__builtin_fmaf(t, XSCALE, XBIAS), 0.0f), 127.0f);
                const int   bin = (int)bf;
                atomicAdd(&s_hist[(cbase + k) * NBINS + bin], pos ? 0x10001u : 1u);
            }
        }
    };

#pragma unroll
    for (int g = 0; g < 4; ++g) {
        if (g < 3) asm volatile("s_waitcnt vmcnt(5)" ::: "memory");
        else       asm volatile("s_waitcnt vmcnt(0)" ::: "memory");
        __builtin_amdgcn_sched_barrier(0);
        compute5(buf[g & 1], g * 5);
        if (g + 2 < 4) {       // refill freed slot with group g+2
#pragma unroll
            for (int k = 0; k < 5; ++k)
                buf[g & 1][k] = gld_f4(pbase + (long)((g + 2) * 5 + k) * HW);
        }
    }

    __syncthreads();

    // Plain coalesced stores of the packed per-block histogram.
    unsigned* gp = g_part + (size_t)blockIdx.x * HSZ;
    for (int i = tid; i < HSZ; i += 512) gp[i] = s_hist[i];
}

// Reduce P[1024][2560] -> H[2560] u64 (cnt lo32 | pos hi32); 320 blocks x 256.
// Last-arriving block (ticket) runs the fused Lovasz scan + final.
__global__ __launch_bounds__(256) void lovasz_reduce(const unsigned* __restrict__ g_part,
                                                     unsigned long long* __restrict__ H,
                                                     unsigned* __restrict__ ctr,
                                                     float* __restrict__ out) {
    const int t   = threadIdx.x;
    const int bin = blockIdx.x * 8 + (t & 7);
    const int rc  = t >> 3;             // replica chunk 0..31 (32 replicas each)
    const unsigned* gp = g_part + bin;

    unsigned vc = 0, vp = 0;
#pragma unroll
    for (int bt = 0; bt < 4; ++bt) {
        unsigned pk = 0;
#pragma unroll
        for (int k = 0; k < 8; ++k)     // 8 * 2048 < 2^16: packed adds safe
            pk += gp[(size_t)(rc * 32 + bt * 8 + k) * HSZ];
        vc += pk & 0xFFFFu;
        vp += pk >> 16;
    }
    __shared__ unsigned s_c[32][8], s_p[32][8];
    s_c[rc][t & 7] = vc;
    s_p[rc][t & 7] = vp;
    __syncthreads();
    if (t < 8) {
        unsigned c = 0, p = 0;
#pragma unroll
        for (int r = 0; r < 32; ++r) { c += s_c[r][t]; p += s_p[r][t]; }
        H[blockIdx.x * 8 + t] = (unsigned long long)c | ((unsigned long long)p << 32);
    }

    // last-block fusion
    __threadfence();
    __syncthreads();
    __shared__ unsigned s_ticket;
    if (t == 0) s_ticket = atomicAdd(ctr, 1u);
    __syncthreads();
    if (s_ticket != NRED - 1) return;
    __threadfence();                    // acquire: others' H stores visible

    __shared__ float cls_sum[NCLS], cls_cnt[NCLS];
    const int wid  = t >> 6;            // 4 waves
    const int lane = t & 63;
#pragma unroll
    for (int it = 0; it < 5; ++it) {
        const int cls = it * 4 + wid;   // 0..19
        // lane covers descending positions d0=2*lane (bin 127-2l), d1 (bin 126-2l)
        const int bin_lo = 126 - 2 * lane;
        const ulonglong2 v = *reinterpret_cast<const ulonglong2*>(H + cls * NBINS + bin_lo);
        const int vc1 = (int)(v.x & 0xFFFFFFFFull), vp1 = (int)(v.x >> 32);  // d1
        const int vc0 = (int)(v.y & 0xFFFFFFFFull), vp0 = (int)(v.y >> 32);  // d0
        const int sc = vc0 + vc1, sp = vp0 + vp1;
        int ic = sc, ip = sp;           // inclusive wave scan over lanes
#pragma unroll
        for (int d = 1; d < 64; d <<= 1) {
            const int tc = __shfl_up(ic, d, 64);
            const int tp = __shfl_up(ip, d, 64);
            if (lane >= d) { ic += tc; ip += tp; }
        }
        const int G   = __shfl(ip, 63, 64);        // total positives
        const int ec0 = ic - sc, ep0 = ip - sp;    // exclusive prefix at d0
        float contrib = 0.0f;
        if (G > 0) {
            const float fG = (float)G;
            auto J = [&](int i, int m) {
                return 1.0f - (fG - (float)m) / (fG + (float)(i - m));
            };
            auto EMID = [&](int bn) {
                const float xm = ((float)bn + 0.5f) * (12.0f / (float)NBINS) - 6.0f;
                return 1.0f / (1.0f + __expf(-xm));
            };
            if (vc0) contrib += EMID(127 - 2 * lane) *
                                (J(ec0 + vc0, ep0 + vp0) - J(ec0, ep0));
            if (vc1) {
                const int ec = ec0 + vc0, ep = ep0 + vp0;
                contrib += EMID(126 - 2 * lane) *
                           (J(ec + vc1, ep + vp1) - J(ec, ep));
            }
        }
#pragma unroll
        for (int d = 32; d > 0; d >>= 1) contrib += __shfl_down(contrib, d, 64);
        if (lane == 0) {
            cls_sum[cls] = contrib;
            cls_cnt[cls] = (G > 0) ? 1.0f : 0.0f;
        }
    }
    __syncthreads();
    if (t == 0) {
        float s = 0.0f, n = 0.0f;
        for (int c = 0; c < NCLS; ++c) { s += cls_sum[c]; n += cls_cnt[c]; }
        out[0] = s / n;
    }
}

extern "C" void kernel_launch(void* const* d_in, const int* in_sizes, int n_in,
                              void* d_out, int out_size, void* d_ws, size_t ws_size,
                              hipStream_t stream) {
    const float* pred  = (const float*)d_in[0];
    const int*   label = (const int*)d_in[1];

    unsigned* g_part = (unsigned*)d_ws;                            // 1024*2560*4B = 10.5 MB
    unsigned long long* H = (unsigned long long*)(g_part + (size_t)NCHUNK * HSZ);
    unsigned* ctr = (unsigned*)(H + HSZ);
    float* out = (float*)d_out;

    lovasz_hist<<<NCHUNK, 512, 0, stream>>>(pred, label, g_part, ctr);
    lovasz_reduce<<<NRED, 256, 0, stream>>>(g_part, H, ctr, out);
}

// Round 15
// 71.541 us; speedup vs baseline: 1.1598x; 1.1598x over previous
//
#include <hip/hip_runtime.h>

#define NBINS  128               // uniform bins in x-space over [-6, 6]
#define NCLS   20
#define CDIM   21
#define HW     (512 * 512)
#define NPIX   (8 * HW)
#define NCHUNK 512
#define CHUNK  (NPIX / NCHUNK)   // 4096 pixels/block; divides HW
#define HSZ    (NCLS * NBINS)    // 2560 packed u32 per block
#define NRED   320               // reduce blocks (8 bins each)
#define XSCALE 10.6666667f       // 128/12
#define XBIAS  64.0f             // 6 * XSCALE

__device__ __forceinline__ float4 gld_f4(const float* p) {
    float4 r;
    asm volatile("global_load_dwordx4 %0, %1, off" : "=v"(r) : "v"(p));
    return r;
}
__device__ __forceinline__ int4 gld_i4(const int* p) {
    int4 r;
    asm volatile("global_load_dwordx4 %0, %1, off" : "=v"(r) : "v"(p));
    return r;
}

// R13's proven hist (39.8 us total): one block = 4096 pixels via 512 threads
// (2 tiles of 2048 px), all 20 classes, binned in x-space (monotone in
// sigmoid; positives bin at -x on the symmetric grid). 8-phase counted-vmcnt
// pipeline, 2 groups ahead (vmcnt(10) steady). launch_bounds(512,4) -> 128
// VGPR budget: no spills around the asm-pinned buffers (R14's (512,6)=85 VGPR
// budget spilled and cost 2x). Output: packed per-block u32 histogram
// (cnt lo16 | pos hi16), plain stores, no pre-zeroing.
__global__ __launch_bounds__(512, 4) void lovasz_hist(const float* __restrict__ pred,
                                                      const int* __restrict__ label,
                                                      unsigned* __restrict__ g_part,
                                                      unsigned* __restrict__ ctr) {
    __shared__ unsigned s_hist[HSZ];   // 10 KB
    const int tid = threadIdx.x;
    if (blockIdx.x == 0 && tid == 0) ctr[0] = 0u;   // reset ticket for reduce

    const long base = (long)blockIdx.x * CHUNK;
    const int  b    = (int)(base / HW);
    const long hw0  = base - (long)b * HW;
    const float* pbase = pred + ((long)b * CDIM + 1) * HW + hw0 + tid * 4;
    const int*   q     = label + base + tid * 4;

    // Prologue: 2 labels + G0 + G1 issued (12 outstanding).
    int4 l[2];
    l[0] = gld_i4(q);
    l[1] = gld_i4(q + 2048);
    float4 buf[3][5];
#pragma unroll
    for (int gg = 0; gg < 2; ++gg)
#pragma unroll
        for (int k = 0; k < 5; ++k)
            buf[gg][k] = gld_f4(pbase + (long)(gg * 5 + k) * HW);

    // zero LDS + barrier under the load latency
    for (int i = tid; i < HSZ; i += 512) s_hist[i] = 0u;
    __syncthreads();

    auto compute5 = [&](const float4* x, int cbase, const int4& lab) {
#pragma unroll
        for (int j = 0; j < 4; ++j) {
            const int lv = (j == 0) ? lab.x : (j == 1) ? lab.y : (j == 2) ? lab.z : lab.w;
#pragma unroll
            for (int k = 0; k < 5; ++k) {
                const float xv = (j == 0) ? x[k].x : (j == 1) ? x[k].y
                               : (j == 2) ? x[k].z : x[k].w;
                const bool  pos = (lv == cbase + k + 1);
                const float t   = pos ? -xv : xv;     // error = sigmoid(t)
                const float bf  = fminf(fmaxf(__builtin_fmaf(t, XSCALE, XBIAS), 0.0f), 127.0f);
                const int   bin = (int)bf;
                atomicAdd(&s_hist[(cbase + k) * NBINS + bin], pos ? 0x10001u : 1u);
            }
        }
    };

#pragma unroll
    for (int g = 0; g < 8; ++g) {
        if (g + 2 < 8) {        // issue group g+2 into buf[(g+2)%3]
            const int gg = g + 2;
#pragma unroll
            for (int k = 0; k < 5; ++k)
                buf[gg % 3][k] =
                    gld_f4(pbase + (long)((gg & 3) * 5 + k) * HW + (gg >> 2) * 2048);
        }
        if (g < 6)       asm volatile("s_waitcnt vmcnt(10)" ::: "memory");
        else if (g == 6) asm volatile("s_waitcnt vmcnt(5)" ::: "memory");
        else             asm volatile("s_waitcnt vmcnt(0)" ::: "memory");
        __builtin_amdgcn_sched_barrier(0);
        compute5(buf[g % 3], (g & 3) * 5, l[g >> 2]);
    }

    __syncthreads();

    // Plain coalesced stores of the packed per-block histogram.
    unsigned* gp = g_part + (size_t)blockIdx.x * HSZ;
    for (int i = tid; i < HSZ; i += 512) gp[i] = s_hist[i];
}

// Reduce P[512][2560] packed -> H[2560] u64 (cnt lo32 | pos hi32); 320 blocks
// x 256 thr, 8 bins/block, thread t: bin t&7, replica chunk t>>3 (16 replicas,
// unpacked every 8: 8*4096 < 2^16). Last-arriving block (ticket) runs the
// fused Lovasz scan + final.
__global__ __launch_bounds__(256) void lovasz_reduce(const unsigned* __restrict__ g_part,
                                                     unsigned long long* __restrict__ H,
                                                     unsigned* __restrict__ ctr,
                                                     float* __restrict__ out) {
    const int t   = threadIdx.x;
    const int bin = blockIdx.x * 8 + (t & 7);
    const int rc  = t >> 3;             // 0..31, 16 replicas each
    const unsigned* gp = g_part + bin;

    unsigned vc = 0, vp = 0;
#pragma unroll
    for (int bt = 0; bt < 2; ++bt) {
        unsigned pk = 0;
#pragma unroll
        for (int k = 0; k < 8; ++k)
            pk += gp[(size_t)(rc * 16 + bt * 8 + k) * HSZ];
        vc += pk & 0xFFFFu;
        vp += pk >> 16;
    }
    __shared__ unsigned s_c[32][8], s_p[32][8];
    s_c[rc][t & 7] = vc;
    s_p[rc][t & 7] = vp;
    __syncthreads();
    if (t < 8) {
        unsigned c = 0, p = 0;
#pragma unroll
        for (int r = 0; r < 32; ++r) { c += s_c[r][t]; p += s_p[r][t]; }
        H[blockIdx.x * 8 + t] = (unsigned long long)c | ((unsigned long long)p << 32);
    }

    // last-block fusion
    __threadfence();
    __syncthreads();
    __shared__ unsigned s_ticket;
    if (t == 0) s_ticket = atomicAdd(ctr, 1u);
    __syncthreads();
    if (s_ticket != NRED - 1) return;
    __threadfence();                    // acquire: others' H stores visible

    __shared__ float cls_sum[NCLS], cls_cnt[NCLS];
    const int wid  = t >> 6;            // 4 waves
    const int lane = t & 63;
#pragma unroll
    for (int it = 0; it < 5; ++it) {
        const int cls = it * 4 + wid;   // 0..19
        // lane covers descending positions d0=2*lane (bin 127-2l), d1 (bin 126-2l)
        const int bin_lo = 126 - 2 * lane;
        const ulonglong2 v = *reinterpret_cast<const ulonglong2*>(H + cls * NBINS + bin_lo);
        const int vc1 = (int)(v.x & 0xFFFFFFFFull), vp1 = (int)(v.x >> 32);  // d1
        const int vc0 = (int)(v.y & 0xFFFFFFFFull), vp0 = (int)(v.y >> 32);  // d0
        const int sc = vc0 + vc1, sp = vp0 + vp1;
        int ic = sc, ip = sp;           // inclusive wave scan over lanes
#pragma unroll
        for (int d = 1; d < 64; d <<= 1) {
            const int tc = __shfl_up(ic, d, 64);
            const int tp = __shfl_up(ip, d, 64);
            if (lane >= d) { ic += tc; ip += tp; }
        }
        const int G   = __shfl(ip, 63, 64);        // total positives
        const int ec0 = ic - sc, ep0 = ip - sp;    // exclusive prefix at d0
        float contrib = 0.0f;
        if (G > 0) {
            const float fG = (float)G;
            auto J = [&](int i, int m) {
                return 1.0f - (fG - (float)m) / (fG + (float)(i - m));
            };
            auto EMID = [&](int bn) {
                const float xm = ((float)bn + 0.5f) * (12.0f / (float)NBINS) - 6.0f;
                return 1.0f / (1.0f + __expf(-xm));
            };
            if (vc0) contrib += EMID(127 - 2 * lane) *
                                (J(ec0 + vc0, ep0 + vp0) - J(ec0, ep0));
            if (vc1) {
                const int ec = ec0 + vc0, ep = ep0 + vp0;
                contrib += EMID(126 - 2 * lane) *
                           (J(ec + vc1, ep + vp1) - J(ec, ep));
            }
        }
#pragma unroll
        for (int d = 32; d > 0; d >>= 1) contrib += __shfl_down(contrib, d, 64);
        if (lane == 0) {
            cls_sum[cls] = contrib;
            cls_cnt[cls] = (G > 0) ? 1.0f : 0.0f;
        }
    }
    __syncthreads();
    if (t == 0) {
        float s = 0.0f, n = 0.0f;
        for (int c = 0; c < NCLS; ++c) { s += cls_sum[c]; n += cls_cnt[c]; }
        out[0] = s / n;
    }
}

extern "C" void kernel_launch(void* const* d_in, const int* in_sizes, int n_in,
                              void* d_out, int out_size, void* d_ws, size_t ws_size,
                              hipStream_t stream) {
    const float* pred  = (const float*)d_in[0];
    const int*   label = (const int*)d_in[1];

    unsigned* g_part = (unsigned*)d_ws;                            // 512*2560*4B = 5.25 MB
    unsigned long long* H = (unsigned long long*)(g_part + (size_t)NCHUNK * HSZ);
    unsigned* ctr = (unsigned*)(H + HSZ);
    float* out = (float*)d_out;

    lovasz_hist<<<NCHUNK, 512, 0, stream>>>(pred, label, g_part, ctr);
    lovasz_reduce<<<NRED, 256, 0, stream>>>(g_part, H, ctr, out);
}

// Round 16
// 40.158 us; speedup vs baseline: 2.0662x; 1.7815x over previous
//
#include <hip/hip_runtime.h>

#define NBINS  128               // uniform bins in x-space over [-6, 6]
#define NCLS   20
#define CDIM   21
#define HW     (512 * 512)
#define NPIX   (8 * HW)
#define NCHUNK 512
#define CHUNK  (NPIX / NCHUNK)   // 4096 pixels/block; divides HW
#define HSZ    (NCLS * NBINS)    // 2560 packed u32 per block
#define XSCALE 10.6666667f       // 128/12
#define XBIAS  64.0f             // 6 * XSCALE

__device__ __forceinline__ float4 gld_f4(const float* p) {
    float4 r;
    asm volatile("global_load_dwordx4 %0, %1, off" : "=v"(r) : "v"(p));
    return r;
}
__device__ __forceinline__ int4 gld_i4(const int* p) {
    int4 r;
    asm volatile("global_load_dwordx4 %0, %1, off" : "=v"(r) : "v"(p));
    return r;
}

// One block = 4096 pixels via 512 threads (2 tiles of 2048 px), all 20 classes,
// binned in x-space (monotone in sigmoid; positives bin at -x, symmetric grid).
// 8-phase counted-vmcnt pipeline (tile g/4, channels (g%4)*5..+4), 2 groups
// ahead -> vmcnt(10) steady. launch_bounds(512,4) = 128-VGPR budget: no spills
// around the asm-pinned buffers (a (512,6)=85-VGPR budget spilled, 2x cost).
// Output: packed per-block u32 histogram (cnt lo16 | pos hi16), plain stores,
// no atomics, no pre-zeroing. NO per-block device fences (R15: threadfence
// fusion = per-XCD L2-writeback storm, +30 us) — kernel boundary orders P->H.
__global__ __launch_bounds__(512, 4) void lovasz_hist(const float* __restrict__ pred,
                                                      const int* __restrict__ label,
                                                      unsigned* __restrict__ g_part) {
    __shared__ unsigned s_hist[HSZ];   // 10 KB
    const int tid = threadIdx.x;

    const long base = (long)blockIdx.x * CHUNK;
    const int  b    = (int)(base / HW);
    const long hw0  = base - (long)b * HW;
    const float* pbase = pred + ((long)b * CDIM + 1) * HW + hw0 + tid * 4;
    const int*   q     = label + base + tid * 4;

    // Prologue: 2 labels + G0 + G1 issued (12 outstanding).
    int4 l[2];
    l[0] = gld_i4(q);
    l[1] = gld_i4(q + 2048);
    float4 buf[3][5];
#pragma unroll
    for (int gg = 0; gg < 2; ++gg)
#pragma unroll
        for (int k = 0; k < 5; ++k)
            buf[gg][k] = gld_f4(pbase + (long)(gg * 5 + k) * HW);

    // zero LDS + barrier under the load latency
    for (int i = tid; i < HSZ; i += 512) s_hist[i] = 0u;
    __syncthreads();

    auto compute5 = [&](const float4* x, int cbase, const int4& lab) {
#pragma unroll
        for (int j = 0; j < 4; ++j) {
            const int lv = (j == 0) ? lab.x : (j == 1) ? lab.y : (j == 2) ? lab.z : lab.w;
#pragma unroll
            for (int k = 0; k < 5; ++k) {
                const float xv = (j == 0) ? x[k].x : (j == 1) ? x[k].y
                               : (j == 2) ? x[k].z : x[k].w;
                const bool  pos = (lv == cbase + k + 1);
                const float t   = pos ? -xv : xv;     // error = sigmoid(t)
                const float bf  = fminf(fmaxf(__builtin_fmaf(t, XSCALE, XBIAS), 0.0f), 127.0f);
                const int   bin = (int)bf;
                atomicAdd(&s_hist[(cbase + k) * NBINS + bin], pos ? 0x10001u : 1u);
            }
        }
    };

#pragma unroll
    for (int g = 0; g < 8; ++g) {
        if (g + 2 < 8) {        // issue group g+2 into buf[(g+2)%3]
            const int gg = g + 2;
#pragma unroll
            for (int k = 0; k < 5; ++k)
                buf[gg % 3][k] =
                    gld_f4(pbase + (long)((gg & 3) * 5 + k) * HW + (gg >> 2) * 2048);
        }
        if (g < 6)       asm volatile("s_waitcnt vmcnt(10)" ::: "memory");
        else if (g == 6) asm volatile("s_waitcnt vmcnt(5)" ::: "memory");
        else             asm volatile("s_waitcnt vmcnt(0)" ::: "memory");
        __builtin_amdgcn_sched_barrier(0);
        compute5(buf[g % 3], (g & 3) * 5, l[g >> 2]);
    }

    __syncthreads();

    // Plain coalesced stores of the packed per-block histogram.
    unsigned* gp = g_part + (size_t)blockIdx.x * HSZ;
    for (int i = tid; i < HSZ; i += 512) gp[i] = s_hist[i];
}

// Parallel reduce: P[512][2560] packed -> H[2560] u64 (cnt lo32 | pos hi32).
// 160 blocks x 256 thr; block bb owns 16 bins; thread t: bin bb*16+(t&15),
// replica chunk t>>4 (32 replicas, unpacked every 8 to avoid 16-bit overflow).
__global__ __launch_bounds__(256) void lovasz_reduce(const unsigned* __restrict__ g_part,
                                                     unsigned long long* __restrict__ H) {
    const int t  = threadIdx.x;
    const int i  = blockIdx.x * 16 + (t & 15);
    const int rc = t >> 4;            // 0..15
    const unsigned* gp = g_part + i;

    unsigned vc = 0, vp = 0;
#pragma unroll
    for (int bt = 0; bt < 4; ++bt) {
        unsigned pk = 0;
#pragma unroll
        for (int k = 0; k < 8; ++k)
            pk += gp[(size_t)(rc * 32 + bt * 8 + k) * HSZ];
        vc += pk & 0xFFFFu;
        vp += pk >> 16;
    }
    __shared__ unsigned s_c[16][16], s_p[16][16];
    s_c[rc][t & 15] = vc;
    s_p[rc][t & 15] = vp;
    __syncthreads();
    if (t < 16) {
        unsigned c = 0, p = 0;
#pragma unroll
        for (int r = 0; r < 16; ++r) { c += s_c[r][t]; p += s_p[r][t]; }
        H[blockIdx.x * 16 + t] = (unsigned long long)c | ((unsigned long long)p << 32);
    }
}

// Fused scan+final: one wave per class (2 bins/lane), shfl butterfly prefix
// scan in descending-error order, Lovasz-grad weighted sum, block reduce.
__global__ __launch_bounds__(1024) void lovasz_scan(const unsigned long long* __restrict__ H,
                                                    float* __restrict__ out) {
    __shared__ float cls_sum[NCLS];
    __shared__ float cls_cnt[NCLS];
    const int wid  = threadIdx.x >> 6;
    const int lane = threadIdx.x & 63;

#pragma unroll
    for (int it = 0; it < 2; ++it) {
        const int cls = it * 16 + wid;
        if (cls < NCLS) {
            // lane covers descending positions d0=2*lane (bin 127-2l), d1 (bin 126-2l)
            const int bin_lo = 126 - 2 * lane;
            const ulonglong2 v = *reinterpret_cast<const ulonglong2*>(H + cls * NBINS + bin_lo);
            const int vc1 = (int)(v.x & 0xFFFFFFFFull), vp1 = (int)(v.x >> 32);  // d1
            const int vc0 = (int)(v.y & 0xFFFFFFFFull), vp0 = (int)(v.y >> 32);  // d0
            const int sc = vc0 + vc1, sp = vp0 + vp1;
            int ic = sc, ip = sp;                 // inclusive wave scan over lanes
#pragma unroll
            for (int d = 1; d < 64; d <<= 1) {
                const int tc = __shfl_up(ic, d, 64);
                const int tp = __shfl_up(ip, d, 64);
                if (lane >= d) { ic += tc; ip += tp; }
            }
            const int G   = __shfl(ip, 63, 64);         // total positives
            const int ec0 = ic - sc, ep0 = ip - sp;     // exclusive prefix at d0
            float contrib = 0.0f;
            if (G > 0) {
                const float fG = (float)G;
                auto J = [&](int i, int m) {
                    return 1.0f - (fG - (float)m) / (fG + (float)(i - m));
                };
                auto EMID = [&](int bn) {
                    const float xm = ((float)bn + 0.5f) * (12.0f / (float)NBINS) - 6.0f;
                    return 1.0f / (1.0f + __expf(-xm));
                };
                if (vc0) {
                    contrib += EMID(127 - 2 * lane) *
                               (J(ec0 + vc0, ep0 + vp0) - J(ec0, ep0));
                }
                if (vc1) {
                    const int ec = ec0 + vc0, ep = ep0 + vp0;
                    contrib += EMID(126 - 2 * lane) *
                               (J(ec + vc1, ep + vp1) - J(ec, ep));
                }
            }
#pragma unroll
            for (int d = 32; d > 0; d >>= 1) contrib += __shfl_down(contrib, d, 64);
            if (lane == 0) {
                cls_sum[cls] = contrib;
                cls_cnt[cls] = (G > 0) ? 1.0f : 0.0f;
            }
        }
    }
    __syncthreads();
    if (threadIdx.x == 0) {
        float s = 0.0f, n = 0.0f;
        for (int c = 0; c < NCLS; ++c) { s += cls_sum[c]; n += cls_cnt[c]; }
        out[0] = s / n;
    }
}

extern "C" void kernel_launch(void* const* d_in, const int* in_sizes, int n_in,
                              void* d_out, int out_size, void* d_ws, size_t ws_size,
                              hipStream_t stream) {
    const float* pred  = (const float*)d_in[0];
    const int*   label = (const int*)d_in[1];

    unsigned* g_part = (unsigned*)d_ws;                       // 512*2560*4B = 5.25 MB
    unsigned long long* H = (unsigned long long*)(g_part + (size_t)NCHUNK * HSZ);
    float* out = (float*)d_out;

    lovasz_hist<<<NCHUNK, 512, 0, stream>>>(pred, label, g_part);
    lovasz_reduce<<<HSZ / 16, 256, 0, stream>>>(g_part, H);
    lovasz_scan<<<1, 1024, 0, stream>>>(H, out);
}